// Round 7
// baseline (240.849 us; speedup 1.0000x reference)
//
#include <hip/hip_runtime.h>
#include <hip/hip_bf16.h>

typedef __bf16 bf16_t;
typedef __bf16 bf16x4 __attribute__((ext_vector_type(4)));
typedef __bf16 bf16x8 __attribute__((ext_vector_type(8)));
typedef float floatx16 __attribute__((ext_vector_type(16)));

#define SEQ    8192
#define DM     1024
#define NHEADS 16
#define HDIM   64

// async global->LDS, 16B per lane; LDS dest is wave-uniform base + lane*16
__device__ __forceinline__ void async_ld16(bf16_t* lds, const bf16_t* g) {
  __builtin_amdgcn_global_load_lds(
      (__attribute__((address_space(1))) void*)g,
      (__attribute__((address_space(3))) void*)lds, 16, 0, 0);
}

// one launch converts x (8192 blocks) + 4 weight matrices (1024 blocks each)
__global__ __launch_bounds__(256)
void cvt_all(const float* __restrict__ x,  const float* __restrict__ qw,
             const float* __restrict__ kw, const float* __restrict__ vw,
             const float* __restrict__ ow,
             bf16_t* __restrict__ Xb,  bf16_t* __restrict__ QWb,
             bf16_t* __restrict__ KWb, bf16_t* __restrict__ VWb,
             bf16_t* __restrict__ OWb) {
  const int b = blockIdx.x;
  const float* in; bf16_t* out; int g;
  if (b < 8192) { in = x; out = Xb; g = b; }
  else {
    const int w  = (b - 8192) >> 10;
    const int wb = (b - 8192) & 1023;
    switch (w) {
      case 0:  in = qw; out = QWb; break;
      case 1:  in = kw; out = KWb; break;
      case 2:  in = vw; out = VWb; break;
      default: in = ow; out = OWb; break;
    }
    g = wb;
  }
  const int idx = (g * 256 + threadIdx.x) * 4;
  float4 v = *(const float4*)(in + idx);
  bf16x4 o = { (bf16_t)v.x, (bf16_t)v.y, (bf16_t)v.z, (bf16_t)v.w };
  *(bf16x4*)(out + idx) = o;
}

// ---------- Shared index/swizzle algebra (verified round-0 core) ----------
// 128x128 tile, BK=64, 4 waves (wave tile 64x64 = 2x2 of 32x32).
// LDS XOR-8 swizzle: slot c of row r holds global chunk c^(r&7); staged via
// inverse-swizzled global source (gc), linear LDS dest.
// A/B frag: m=lane&31, k=(lane>>5)*8+j. C/D: col=lane&31,
// row=(reg&3)+8*(reg>>2)+4*(lane>>5)  [m74/m101].

// ---------- gemm_proj: DOUBLE-BUFFERED variant (round-7 A/B arm) ----------
// T3-minimum recipe: stage(next) issued BEFORE the compute phase; ONE
// __syncthreads per K-tile (its vmcnt(0) drain lands AFTER ~300cy of
// ds_read+MFMA, not right after issue). The rounds-1-3 failure mode
// (compiler alias-drain before ds_read) is addressed by 2x-unrolling the
// K-loop so buffer indices are COMPILE-TIME constants -> sA[0]/sA[1] are
// provably disjoint LDS ranges. 64KB LDS -> 2 blocks/CU (grid 512 = exactly
// 2/CU, zero tail). Control: gemm_outk keeps the single-buffer core.
__global__ __launch_bounds__(256)
void gemm_proj(const bf16_t* __restrict__ A, const bf16_t* __restrict__ B,
               bf16_t* __restrict__ C, float scl)
{
  constexpr int Kdim = DM;
  __shared__ __attribute__((aligned(16))) bf16_t sA[2][128 * 64];   // 32 KB
  __shared__ __attribute__((aligned(16))) bf16_t sB[2][128 * 64];   // 32 KB

  const int tid  = threadIdx.x;
  const int wave = tid >> 6;
  const int lane = tid & 63;
  const int l31  = lane & 31;
  const int half = lane >> 5;
  const int wr   = (wave >> 1) * 64;
  const int wc   = (wave & 1) * 64;

  const int gc = (lane & 7) ^ ((lane >> 3) & 7);   // swizzled fetch chunk
  const size_t arow0 = (size_t)blockIdx.x * 128 + wave * 32 + (lane >> 3);
  const size_t brow0 = (size_t)blockIdx.y * 128 + wave * 32 + (lane >> 3);
  const bf16_t* Ag = A + arow0 * Kdim + gc * 8;
  const bf16_t* Bg = B + brow0 * Kdim + gc * 8;

  floatx16 acc[2][2];
  #pragma unroll
  for (int i = 0; i < 2; ++i)
    #pragma unroll
    for (int j = 0; j < 2; ++j)
      acc[i][j] = (floatx16)(0.0f);

  const int sw = l31 & 7;                 // read-side swizzle key

  auto stage = [&](int buf, int ko) {
    #pragma unroll
    for (int n = 0; n < 4; ++n) {
      async_ld16(&sA[buf][(wave * 32 + n * 8) * 64], Ag + (size_t)n * 8 * Kdim + ko);
      async_ld16(&sB[buf][(wave * 32 + n * 8) * 64], Bg + (size_t)n * 8 * Kdim + ko);
    }
  };
  auto compute = [&](int buf) {
    #pragma unroll
    for (int s = 0; s < 4; ++s) {         // four K=16 sub-steps
      const int ck   = s * 2 + half;
      const int slot = (ck ^ sw) * 8;
      bf16x8 af[2], bfr[2];
      #pragma unroll
      for (int mi = 0; mi < 2; ++mi)
        af[mi] = *(const bf16x8*)&sA[buf][(wr + mi * 32 + l31) * 64 + slot];
      #pragma unroll
      for (int ni = 0; ni < 2; ++ni)
        bfr[ni] = *(const bf16x8*)&sB[buf][(wc + ni * 32 + l31) * 64 + slot];
      #pragma unroll
      for (int mi = 0; mi < 2; ++mi)
        #pragma unroll
        for (int ni = 0; ni < 2; ++ni)
          acc[mi][ni] = __builtin_amdgcn_mfma_f32_32x32x16_bf16(af[mi], bfr[ni], acc[mi][ni], 0, 0, 0);
    }
  };

  stage(0, 0);
  __syncthreads();
  for (int kp = 0; kp < 8; ++kp) {        // 2 K-tiles per trip; buf idx constant
    const int ko = kp * 128;
    stage(1, ko + 64);                    // tile 2kp+1 always exists (16 tiles)
    compute(0);
    __syncthreads();                      // drains stage(1); readers of buf0 done
    if (ko + 128 < Kdim) stage(0, ko + 128);
    compute(1);
    __syncthreads();
  }

  const int crow0 = blockIdx.x * 128 + wr + 4 * half;
  const int ccol0 = blockIdx.y * 128 + wc + l31;
  #pragma unroll
  for (int mi = 0; mi < 2; ++mi)
    #pragma unroll
    for (int ni = 0; ni < 2; ++ni)
      #pragma unroll
      for (int r = 0; r < 16; ++r) {
        const int row = crow0 + mi * 32 + (r & 3) + 8 * (r >> 2);
        C[(size_t)row * DM + (ccol0 + ni * 32)] = (bf16_t)(acc[mi][ni][r] * scl);
      }
}

// ---------- gemm_outk: single-buffer PROVEN core (in-round control) ----------
__global__ __launch_bounds__(256)
void gemm_outk(const bf16_t* __restrict__ A, const bf16_t* __restrict__ B,
               float* __restrict__ C)
{
  constexpr int Kdim = DM;
  __shared__ __attribute__((aligned(16))) bf16_t sA[128 * 64];   // 16 KB
  __shared__ __attribute__((aligned(16))) bf16_t sB[128 * 64];   // 16 KB

  const int tid  = threadIdx.x;
  const int wave = tid >> 6;
  const int lane = tid & 63;
  const int l31  = lane & 31;
  const int half = lane >> 5;
  const int wr   = (wave >> 1) * 64;
  const int wc   = (wave & 1) * 64;

  const int gc = (lane & 7) ^ ((lane >> 3) & 7);
  const size_t arow0 = (size_t)blockIdx.x * 128 + wave * 32 + (lane >> 3);
  const size_t brow0 = (size_t)blockIdx.y * 128 + wave * 32 + (lane >> 3);
  const bf16_t* Ag = A + arow0 * Kdim + gc * 8;
  const bf16_t* Bg = B + brow0 * Kdim + gc * 8;
  bf16_t* sAw = sA + wave * 32 * 64;
  bf16_t* sBw = sB + wave * 32 * 64;

  floatx16 acc[2][2];
  #pragma unroll
  for (int i = 0; i < 2; ++i)
    #pragma unroll
    for (int j = 0; j < 2; ++j)
      acc[i][j] = (floatx16)(0.0f);

  const int sw = l31 & 7;

  for (int ko = 0; ko < Kdim; ko += 64) {
    #pragma unroll
    for (int n = 0; n < 4; ++n) {
      async_ld16(sAw + n * 512, Ag + (size_t)n * 8 * Kdim + ko);
      async_ld16(sBw + n * 512, Bg + (size_t)n * 8 * Kdim + ko);
    }
    __syncthreads();

    #pragma unroll
    for (int s = 0; s < 4; ++s) {
      const int ck   = s * 2 + half;
      const int slot = (ck ^ sw) * 8;
      bf16x8 af[2], bfr[2];
      #pragma unroll
      for (int mi = 0; mi < 2; ++mi)
        af[mi] = *(const bf16x8*)&sA[(wr + mi * 32 + l31) * 64 + slot];
      #pragma unroll
      for (int ni = 0; ni < 2; ++ni)
        bfr[ni] = *(const bf16x8*)&sB[(wc + ni * 32 + l31) * 64 + slot];

      #pragma unroll
      for (int mi = 0; mi < 2; ++mi)
        #pragma unroll
        for (int ni = 0; ni < 2; ++ni)
          acc[mi][ni] = __builtin_amdgcn_mfma_f32_32x32x16_bf16(af[mi], bfr[ni], acc[mi][ni], 0, 0, 0);
    }

    __syncthreads();
  }

  const int crow0 = blockIdx.x * 128 + wr + 4 * half;
  const int ccol0 = blockIdx.y * 128 + wc + l31;
  #pragma unroll
  for (int mi = 0; mi < 2; ++mi)
    #pragma unroll
    for (int ni = 0; ni < 2; ++ni)
      #pragma unroll
      for (int r = 0; r < 16; ++r) {
        const int row = crow0 + mi * 32 + (r & 3) + 8 * (r >> 2);
        C[(size_t)row * DM + (ccol0 + ni * 32)] = acc[mi][ni][r];
      }
}

// ---------- Attention: 1 WAVE PER QUERY (round 7) ----------
// Round-6 counters: 41.3us, VALUBusy 54%, Occupancy 28%, MfmaUtil 0, HBM 25%.
// The 4-way sub-split paid LDS merges + __syncthreads at LOW occupancy -- the
// wrong trade. Here: 4 queries/block (4 waves, 256 thr), NO LDS, NO barriers;
// each wave runs the full <=14-position online-softmax chain (body verbatim
// from the verified split-wave kernel, stride 1) with depth-1 prefetch.
// 2048 blocks -> 8 blocks/CU, ~24+ waves/CU: TLP hides the serial chain.
// Lane L owns dims [16L,16L+16) (head = L>>2); Q arrives pre-scaled.
// XCD-chunked swizzle: 256-block chunks (1024 consecutive queries) per XCD.
__global__ __launch_bounds__(256)
void dilated_attn(const bf16_t* __restrict__ Q, const bf16_t* __restrict__ K,
                  const bf16_t* __restrict__ V, bf16_t* O)
{
  const int lane = threadIdx.x & 63;
  const int wv   = threadIdx.x >> 6;   // 0..3
  const int bid  = blockIdx.x;         // 0..2047
  const int i    = ((bid & 7) * 256 + (bid >> 3)) * 4 + wv;
  const size_t base = (size_t)i * DM + lane * 16;

  bf16x8 q0 = *(const bf16x8*)(Q + base);
  bf16x8 q1 = *(const bf16x8*)(Q + base + 8);
  float qf[16];
  #pragma unroll
  for (int j = 0; j < 8; ++j) { qf[j] = (float)q0[j]; qf[j + 8] = (float)q1[j]; }

  // npos = 1 (i==0) else floor(log2 i) + 2   (wave-uniform); max 14
  const int npos = (i == 0) ? 1 : (33 - __builtin_clz((unsigned)i));
  auto pos_addr = [&](int t) -> size_t {
    const int off = (t == 0) ? 0 : (1 << (t - 1));
    return (size_t)(i - off) * DM + lane * 16;
  };

  float m = -INFINITY, l = 0.0f;
  float acc[16];
  #pragma unroll
  for (int j = 0; j < 16; ++j) acc[j] = 0.0f;

  // t=0 always valid (npos >= 1)
  {
    size_t a = base;                     // pos_addr(0)
    bf16x8 k0 = *(const bf16x8*)(K + a), k1 = *(const bf16x8*)(K + a + 8);
    bf16x8 v0 = *(const bf16x8*)(V + a), v1 = *(const bf16x8*)(V + a + 8);
    int t = 0;
    while (true) {
      const int tn = t + 1;
      const bool more = (tn < npos);     // wave-uniform
      bf16x8 nk0, nk1, nv0, nv1;
      if (more) {                        // prefetch next position
        const size_t na = pos_addr(tn);
        nk0 = *(const bf16x8*)(K + na); nk1 = *(const bf16x8*)(K + na + 8);
        nv0 = *(const bf16x8*)(V + na); nv1 = *(const bf16x8*)(V + na + 8);
      }

      float sc = 0.0f;
      #pragma unroll
      for (int j = 0; j < 8; ++j) sc += qf[j] * (float)k0[j] + qf[j + 8] * (float)k1[j];
      sc += __shfl_xor(sc, 1, 64);       // sum across the 4 lanes of this head
      sc += __shfl_xor(sc, 2, 64);

      float mn = fmaxf(m, sc);
      float co = __expf(m - mn);
      float w  = __expf(sc - mn);
      l = l * co + w;
      m = mn;
      #pragma unroll
      for (int j = 0; j < 8; ++j) {
        acc[j]     = acc[j]     * co + w * (float)v0[j];
        acc[j + 8] = acc[j + 8] * co + w * (float)v1[j];
      }

      if (!more) break;
      k0 = nk0; k1 = nk1; v0 = nv0; v1 = nv1;
      t = tn;
    }
  }

  const float inv = 1.0f / l;
  bf16x8 o0, o1;
  #pragma unroll
  for (int j = 0; j < 8; ++j) {
    o0[j] = (bf16_t)(acc[j]     * inv);
    o1[j] = (bf16_t)(acc[j + 8] * inv);
  }
  *(bf16x8*)(O + base)     = o0;
  *(bf16x8*)(O + base + 8) = o1;
}

extern "C" void kernel_launch(void* const* d_in, const int* in_sizes, int n_in,
                              void* d_out, int out_size, void* d_ws, size_t ws_size,
                              hipStream_t stream) {
  (void)in_sizes; (void)n_in; (void)out_size; (void)ws_size;
  const float* x  = (const float*)d_in[0];
  const float* qw = (const float*)d_in[1];
  const float* kw = (const float*)d_in[2];
  const float* vw = (const float*)d_in[3];
  const float* ow = (const float*)d_in[4];
  // d_in[5] (positions) and d_in[6] (attend_mask) recomputed analytically in-kernel
  float* out = (float*)d_out;

  bf16_t* Xb  = (bf16_t*)d_ws;                       // 8192x1024
  bf16_t* Qb  = Xb  + (size_t)SEQ * DM;
  bf16_t* Kb  = Qb  + (size_t)SEQ * DM;
  bf16_t* Vb  = Kb  + (size_t)SEQ * DM;
  bf16_t* QWb = Vb  + (size_t)SEQ * DM;              // 1024x1024 x4
  bf16_t* KWb = QWb + (size_t)DM * DM;
  bf16_t* VWb = KWb + (size_t)DM * DM;
  bf16_t* OWb = VWb + (size_t)DM * DM;
  bf16_t* AO  = Qb;  // alias Q: each attn wave reads its own q row before writing it

  cvt_all<<<dim3(8192 + 4096), dim3(256), 0, stream>>>(x, qw, kw, vw, ow,
                                                       Xb, QWb, KWb, VWb, OWb);

  dim3 pg(SEQ / 128, DM / 128);
  gemm_proj<<<pg, dim3(256), 0, stream>>>(Xb, QWb, Qb, 0.125f);  // fold 1/sqrt(64)
  gemm_proj<<<pg, dim3(256), 0, stream>>>(Xb, KWb, Kb, 1.0f);
  gemm_proj<<<pg, dim3(256), 0, stream>>>(Xb, VWb, Vb, 1.0f);
  dilated_attn<<<dim3(SEQ / 4), dim3(256), 0, stream>>>(Qb, Kb, Vb, AO);
  gemm_outk<<<pg, dim3(256), 0, stream>>>(AO, OWb, out);
}

// Round 8
// 222.061 us; speedup vs baseline: 1.0846x; 1.0846x over previous
//
#include <hip/hip_runtime.h>
#include <hip/hip_bf16.h>

typedef __bf16 bf16_t;
typedef __bf16 bf16x4 __attribute__((ext_vector_type(4)));
typedef __bf16 bf16x8 __attribute__((ext_vector_type(8)));
typedef float floatx16 __attribute__((ext_vector_type(16)));

#define SEQ    8192
#define DM     1024
#define NHEADS 16
#define HDIM   64

// async global->LDS, 16B per lane; LDS dest is wave-uniform base + lane*16
__device__ __forceinline__ void async_ld16(bf16_t* lds, const bf16_t* g) {
  __builtin_amdgcn_global_load_lds(
      (__attribute__((address_space(1))) void*)g,
      (__attribute__((address_space(3))) void*)lds, 16, 0, 0);
}

// one launch converts x (8192 blocks) + 4 weight matrices (1024 blocks each)
__global__ __launch_bounds__(256)
void cvt_all(const float* __restrict__ x,  const float* __restrict__ qw,
             const float* __restrict__ kw, const float* __restrict__ vw,
             const float* __restrict__ ow,
             bf16_t* __restrict__ Xb,  bf16_t* __restrict__ QWb,
             bf16_t* __restrict__ KWb, bf16_t* __restrict__ VWb,
             bf16_t* __restrict__ OWb) {
  const int b = blockIdx.x;
  const float* in; bf16_t* out; int g;
  if (b < 8192) { in = x; out = Xb; g = b; }
  else {
    const int w  = (b - 8192) >> 10;
    const int wb = (b - 8192) & 1023;
    switch (w) {
      case 0:  in = qw; out = QWb; break;
      case 1:  in = kw; out = KWb; break;
      case 2:  in = vw; out = VWb; break;
      default: in = ow; out = OWb; break;
    }
    g = wb;
  }
  const int idx = (g * 256 + threadIdx.x) * 4;
  float4 v = *(const float4*)(in + idx);
  bf16x4 o = { (bf16_t)v.x, (bf16_t)v.y, (bf16_t)v.z, (bf16_t)v.w };
  *(bf16x4*)(out + idx) = o;
}

// ---------- Verified 128x128 single-buffer GEMM core (845 TF class) ----------
// 128x128 tile, BK=64, 4 waves (wave tile 64x64), 32KB LDS, 80 VGPR ->
// ~5 co-resident blocks/CU; drain stall at __syncthreads hidden by
// INTER-BLOCK overlap (m114). GEMM ledger (rounds 1-4,7): 6/6 variants that
// reduced blocks/CU (bigger tile, dbuf 64KB, in-flight vmcnt schedules)
// regressed. This structure is the accepted local optimum; DO NOT add
// double-buffering or grow the wave tile without a new mechanism.
// LDS XOR-8 swizzle: slot c of row r holds global chunk c^(r&7).
// A/B frag: m=lane&31, k=(lane>>5)*8+j. C/D: col=lane&31,
// row=(reg&3)+8*(reg>>2)+4*(lane>>5)  [m74/m101].
template <typename OutT>
__device__ __forceinline__ void gemm128_core(
    const bf16_t* __restrict__ A, const bf16_t* __restrict__ B,
    OutT* __restrict__ C, float scl)
{
  constexpr int Kdim = DM;
  __shared__ __attribute__((aligned(16))) bf16_t sA[128 * 64];   // 16 KB
  __shared__ __attribute__((aligned(16))) bf16_t sB[128 * 64];   // 16 KB

  const int tid  = threadIdx.x;
  const int wave = tid >> 6;
  const int lane = tid & 63;
  const int l31  = lane & 31;
  const int half = lane >> 5;
  const int wr   = (wave >> 1) * 64;
  const int wc   = (wave & 1) * 64;

  const int gc = (lane & 7) ^ ((lane >> 3) & 7);   // swizzled fetch chunk
  const size_t arow0 = (size_t)blockIdx.x * 128 + wave * 32 + (lane >> 3);
  const size_t brow0 = (size_t)blockIdx.y * 128 + wave * 32 + (lane >> 3);
  const bf16_t* Ag = A + arow0 * Kdim + gc * 8;
  const bf16_t* Bg = B + brow0 * Kdim + gc * 8;
  bf16_t* sAw = sA + wave * 32 * 64;
  bf16_t* sBw = sB + wave * 32 * 64;

  floatx16 acc[2][2];
  #pragma unroll
  for (int i = 0; i < 2; ++i)
    #pragma unroll
    for (int j = 0; j < 2; ++j)
      acc[i][j] = (floatx16)(0.0f);

  const int sw = l31 & 7;                 // read-side swizzle key

  for (int ko = 0; ko < Kdim; ko += 64) {
    #pragma unroll
    for (int n = 0; n < 4; ++n) {
      async_ld16(sAw + n * 512, Ag + (size_t)n * 8 * Kdim + ko);
      async_ld16(sBw + n * 512, Bg + (size_t)n * 8 * Kdim + ko);
    }
    __syncthreads();   // drains vmcnt, then barrier

    #pragma unroll
    for (int s = 0; s < 4; ++s) {         // four K=16 sub-steps
      const int ck   = s * 2 + half;
      const int slot = (ck ^ sw) * 8;
      bf16x8 af[2], bfr[2];
      #pragma unroll
      for (int mi = 0; mi < 2; ++mi)
        af[mi] = *(const bf16x8*)&sA[(wr + mi * 32 + l31) * 64 + slot];
      #pragma unroll
      for (int ni = 0; ni < 2; ++ni)
        bfr[ni] = *(const bf16x8*)&sB[(wc + ni * 32 + l31) * 64 + slot];

      #pragma unroll
      for (int mi = 0; mi < 2; ++mi)
        #pragma unroll
        for (int ni = 0; ni < 2; ++ni)
          acc[mi][ni] = __builtin_amdgcn_mfma_f32_32x32x16_bf16(af[mi], bfr[ni], acc[mi][ni], 0, 0, 0);
    }

    __syncthreads();   // protect LDS before next stage overwrites
  }

  const int crow0 = blockIdx.x * 128 + wr + 4 * half;
  const int ccol0 = blockIdx.y * 128 + wc + l31;
  #pragma unroll
  for (int mi = 0; mi < 2; ++mi)
    #pragma unroll
    for (int ni = 0; ni < 2; ++ni)
      #pragma unroll
      for (int r = 0; r < 16; ++r) {
        const int row = crow0 + mi * 32 + (r & 3) + 8 * (r >> 2);
        C[(size_t)row * DM + (ccol0 + ni * 32)] = (OutT)(acc[mi][ni][r] * scl);
      }
}

__global__ __launch_bounds__(256)
void gemm_proj(const bf16_t* __restrict__ A, const bf16_t* __restrict__ B,
               bf16_t* __restrict__ C, float scl)
{
  gemm128_core<bf16_t>(A, B, C, scl);
}

__global__ __launch_bounds__(256)
void gemm_outk(const bf16_t* __restrict__ A, const bf16_t* __restrict__ B,
               float* __restrict__ C)
{
  gemm128_core<float>(A, B, C, 1.0f);
}

// ---------- Attention: 1 wave/query, 2-STREAM IN-REGISTER SPLIT (round 8) ----------
// Round-7 counters: 43.5us, VALUBusy 35%, Occ 35%, HBM 2.8 TB/s (45% of
// achievable -> NOT HBM-bound), conflicts 0. Diagnosis: (a) XCD-chunked map
// gave XCD0 queries [0,1024) (small npos) and XCD7 [7168,8192) (npos=14) ->
// ~1.5x inter-XCD work imbalance; (b) 14-step serial dependent chain at
// depth-1 prefetch exposes ~400cy/step.
// Fixes: (a) balanced interleave: XCD x gets chunks {x,8+x,16+x,24+x} of 256
// consecutive queries (equal sum-npos per XCD; window rows of a chunk ~1MB
// << 4MB L2). (b) positions split even/odd into TWO independent online-
// softmax states in one wave (no LDS, no barriers), merged in-register at the
// end (mE finite since t=0 valid; empty D-stream has mD=-inf -> cb=0 no-op).
// Pair-wise X/Y double-buffer: while computing pair p, pair p+1's 8 loads are
// in flight -> chain 14 -> 7 waits, 2x MLP. Cost: ~120 VGPR -> 4 waves/SIMD
// (discriminating experiment: latency-bound -> big win; if regression ->
// occupancy-hiding was binding, revert to 40-VGPR form).
__global__ __launch_bounds__(256)
void dilated_attn(const bf16_t* __restrict__ Q, const bf16_t* __restrict__ K,
                  const bf16_t* __restrict__ V, bf16_t* O)
{
  const int lane = threadIdx.x & 63;
  const int wv   = threadIdx.x >> 6;   // 0..3
  const int bid  = blockIdx.x;         // 0..2047
  // balanced bijective map: x=bid&7 (XCD), j=bid>>3; chunk = x + (j>>6)*8
  const int jj   = bid >> 3;
  const int chunk= (bid & 7) + ((jj >> 6) << 3);       // 0..31
  const int i    = chunk * 256 + (jj & 63) * 4 + wv;   // query index
  const size_t base = (size_t)i * DM + lane * 16;

  bf16x8 q0 = *(const bf16x8*)(Q + base);
  bf16x8 q1 = *(const bf16x8*)(Q + base + 8);
  float qf[16];
  #pragma unroll
  for (int j = 0; j < 8; ++j) { qf[j] = (float)q0[j]; qf[j + 8] = (float)q1[j]; }

  // npos = 1 (i==0) else floor(log2 i) + 2   (wave-uniform); max 14
  const int npos = (i == 0) ? 1 : (33 - __builtin_clz((unsigned)i));
  auto pos_addr = [&](int t) -> size_t {
    const int off = (t == 0) ? 0 : (1 << (t - 1));
    return (size_t)(i - off) * DM + lane * 16;
  };
  auto ld_pos = [&](int t, bf16x8& k0, bf16x8& k1, bf16x8& v0, bf16x8& v1) {
    const size_t a = pos_addr(t);
    k0 = *(const bf16x8*)(K + a); k1 = *(const bf16x8*)(K + a + 8);
    v0 = *(const bf16x8*)(V + a); v1 = *(const bf16x8*)(V + a + 8);
  };

  // two independent online-softmax states: E (even t), D (odd t)
  float mE = -INFINITY, lE = 0.0f, mD = -INFINITY, lD = 0.0f;
  float aE[16], aD[16];
  #pragma unroll
  for (int j = 0; j < 16; ++j) { aE[j] = 0.0f; aD[j] = 0.0f; }

  auto step = [&](float& m, float& l, float* acc,
                  const bf16x8& k0, const bf16x8& k1,
                  const bf16x8& v0, const bf16x8& v1) {
    float sc = 0.0f;
    #pragma unroll
    for (int j = 0; j < 8; ++j) sc += qf[j] * (float)k0[j] + qf[j + 8] * (float)k1[j];
    sc += __shfl_xor(sc, 1, 64);         // sum across the 4 lanes of this head
    sc += __shfl_xor(sc, 2, 64);
    const float mn = fmaxf(m, sc);
    const float co = __expf(m - mn);
    const float w  = __expf(sc - mn);
    l = l * co + w;
    m = mn;
    #pragma unroll
    for (int j = 0; j < 8; ++j) {
      acc[j]     = acc[j]     * co + w * (float)v0[j];
      acc[j + 8] = acc[j + 8] * co + w * (float)v1[j];
    }
  };

  // pair pipeline: X holds pair (t, t+1), Y holds pair (t+2, t+3)
  bf16x8 xk0a, xk1a, xv0a, xv1a, xk0b, xk1b, xv0b, xv1b;
  bf16x8 yk0a, yk1a, yv0a, yv1a, yk0b, yk1b, yv0b, yv1b;

  ld_pos(0, xk0a, xk1a, xv0a, xv1a);
  if (1 < npos) ld_pos(1, xk0b, xk1b, xv0b, xv1b);

  for (int t = 0; ; t += 4) {
    const bool pe1 = (t + 2) < npos;     // Y pair exists (wave-uniform)
    if (pe1)            ld_pos(t + 2, yk0a, yk1a, yv0a, yv1a);
    const bool pd1 = (t + 3) < npos;
    if (pd1)            ld_pos(t + 3, yk0b, yk1b, yv0b, yv1b);
    step(mE, lE, aE, xk0a, xk1a, xv0a, xv1a);
    if ((t + 1) < npos) step(mD, lD, aD, xk0b, xk1b, xv0b, xv1b);
    if (!pe1) break;

    const bool pe2 = (t + 4) < npos;     // next X pair exists
    if (pe2)            ld_pos(t + 4, xk0a, xk1a, xv0a, xv1a);
    if ((t + 5) < npos) ld_pos(t + 5, xk0b, xk1b, xv0b, xv1b);
    step(mE, lE, aE, yk0a, yk1a, yv0a, yv1a);
    if (pd1)            step(mD, lD, aD, yk0b, yk1b, yv0b, yv1b);
    if (!pe2) break;
  }

  // in-register merge of D into E (proven identity; npos==1 -> mD=-inf -> cb=0)
  const float mt = fmaxf(mE, mD);
  const float ca = __expf(mE - mt);
  const float cb = __expf(mD - mt);
  const float inv = 1.0f / (lE * ca + lD * cb);
  bf16x8 o0, o1;
  #pragma unroll
  for (int j = 0; j < 8; ++j) {
    o0[j] = (bf16_t)((aE[j]     * ca + aD[j]     * cb) * inv);
    o1[j] = (bf16_t)((aE[j + 8] * ca + aD[j + 8] * cb) * inv);
  }
  *(bf16x8*)(O + base)     = o0;
  *(bf16x8*)(O + base + 8) = o1;
}

extern "C" void kernel_launch(void* const* d_in, const int* in_sizes, int n_in,
                              void* d_out, int out_size, void* d_ws, size_t ws_size,
                              hipStream_t stream) {
  (void)in_sizes; (void)n_in; (void)out_size; (void)ws_size;
  const float* x  = (const float*)d_in[0];
  const float* qw = (const float*)d_in[1];
  const float* kw = (const float*)d_in[2];
  const float* vw = (const float*)d_in[3];
  const float* ow = (const float*)d_in[4];
  // d_in[5] (positions) and d_in[6] (attend_mask) recomputed analytically in-kernel
  float* out = (float*)d_out;

  bf16_t* Xb  = (bf16_t*)d_ws;                       // 8192x1024
  bf16_t* Qb  = Xb  + (size_t)SEQ * DM;
  bf16_t* Kb  = Qb  + (size_t)SEQ * DM;
  bf16_t* Vb  = Kb  + (size_t)SEQ * DM;
  bf16_t* QWb = Vb  + (size_t)SEQ * DM;              // 1024x1024 x4
  bf16_t* KWb = QWb + (size_t)DM * DM;
  bf16_t* VWb = KWb + (size_t)DM * DM;
  bf16_t* OWb = VWb + (size_t)DM * DM;
  bf16_t* AO  = Qb;  // alias Q: each attn wave reads its own q row before writing it

  cvt_all<<<dim3(8192 + 4096), dim3(256), 0, stream>>>(x, qw, kw, vw, ow,
                                                       Xb, QWb, KWb, VWb, OWb);

  dim3 pg(SEQ / 128, DM / 128);
  gemm_proj<<<pg, dim3(256), 0, stream>>>(Xb, QWb, Qb, 0.125f);  // fold 1/sqrt(64)
  gemm_proj<<<pg, dim3(256), 0, stream>>>(Xb, KWb, Kb, 1.0f);
  gemm_proj<<<pg, dim3(256), 0, stream>>>(Xb, VWb, Vb, 1.0f);
  dilated_attn<<<dim3(SEQ / 4), dim3(256), 0, stream>>>(Qb, Kb, Vb, AO);
  gemm_outk<<<pg, dim3(256), 0, stream>>>(AO, OWb, out);
}